// Round 2
// baseline (1167.627 us; speedup 1.0000x reference)
//
#include <hip/hip_runtime.h>

// Problem constants
#define BB    4
#define LL    4096
#define DM    1024
#define HH    16
#define SEGC  64
#define HDC   64
#define NSEGC 64
#define NEGV  -1.0e10f

typedef __bf16 bf16x8 __attribute__((ext_vector_type(8)));
typedef float  f32x4  __attribute__((ext_vector_type(4)));

__device__ __forceinline__ float bflo(unsigned int u) {
  union { unsigned int u; float f; } x; x.u = u << 16; return x.f;
}
__device__ __forceinline__ float bfhi(unsigned int u) {
  union { unsigned int u; float f; } x; x.u = u & 0xffff0000u; return x.f;
}
__device__ __forceinline__ float bf2f(unsigned short s) {
  union { unsigned int u; float f; } x; x.u = ((unsigned int)s) << 16; return x.f;
}
__device__ __forceinline__ unsigned short f2bf(float f) {
  union { float f; unsigned int u; } x; x.f = f;
  unsigned int u = x.u;
  return (unsigned short)((u + 0x7fffu + ((u >> 16) & 1u)) >> 16);
}

// copy 16 bf16 from global (16B-aligned) to LDS (4B-aligned)
__device__ __forceinline__ void g2lds16(unsigned short* dst, const unsigned short* src) {
  int4 a = *(const int4*)(src);
  int4 b = *(const int4*)(src + 8);
  unsigned int* d = (unsigned int*)dst;
  const unsigned int* pa = (const unsigned int*)&a;
  const unsigned int* pb = (const unsigned int*)&b;
  d[0]=pa[0]; d[1]=pa[1]; d[2]=pa[2]; d[3]=pa[3];
  d[4]=pb[0]; d[5]=pb[1]; d[6]=pb[2]; d[7]=pb[3];
}

// ---------------------------------------------------------------------------
// Generic GEMM: C[M x 1024] = scale * (A[M x 1024] @ W[1024 x 1024])
// A: f32 or bf16 (template). W: f32 (converted to bf16 in staging).
// C: f32 or bf16 (template). 128x128 tile, BK=32, 4 waves (2x2), each wave
// 4x4 of 16x16x32 bf16 MFMA, fp32 accumulate.
// ---------------------------------------------------------------------------
template <bool A_F32, bool C_F32>
__global__ __launch_bounds__(256) void gemm_k(
    const void* __restrict__ Av,
    const float* __restrict__ W,
    void* __restrict__ Cv,
    float scale)
{
  __shared__ unsigned short As[128 * 32];   // [m][k], stride 32
  __shared__ unsigned short Bs[128 * 40];   // [n][k], stride 40 (16B-aligned rows)

  const int t    = threadIdx.x;
  const int wave = t >> 6;
  const int lane = t & 63;
  const int l15  = lane & 15;
  const int q4   = lane >> 4;
  const int wm   = wave >> 1;
  const int wn   = wave & 1;
  const int m0   = blockIdx.x * 128;
  const int n0   = blockIdx.y * 128;

  f32x4 acc[4][4];
  #pragma unroll
  for (int i = 0; i < 4; i++)
    #pragma unroll
    for (int j = 0; j < 4; j++)
      acc[i][j] = (f32x4){0.f, 0.f, 0.f, 0.f};

  const int am = t >> 1;            // 0..127
  const int ak = (t & 1) * 16;      // 0 / 16

  for (int k0 = 0; k0 < 1024; k0 += 32) {
    __syncthreads();
    // stage A tile [128][32] as bf16
    if (A_F32) {
      const float* src = (const float*)Av + (size_t)(m0 + am) * 1024 + k0 + ak;
      unsigned short tmp[16];
      #pragma unroll
      for (int i = 0; i < 4; i++) {
        float4 f = *(const float4*)(src + i * 4);
        tmp[4 * i + 0] = f2bf(f.x);
        tmp[4 * i + 1] = f2bf(f.y);
        tmp[4 * i + 2] = f2bf(f.z);
        tmp[4 * i + 3] = f2bf(f.w);
      }
      int4* dst = (int4*)(As + am * 32 + ak);
      dst[0] = ((const int4*)tmp)[0];
      dst[1] = ((const int4*)tmp)[1];
    } else {
      const unsigned short* src = (const unsigned short*)Av + (size_t)(m0 + am) * 1024 + k0 + ak;
      int4 v0 = *(const int4*)(src);
      int4 v1 = *(const int4*)(src + 8);
      int4* dst = (int4*)(As + am * 32 + ak);
      dst[0] = v0; dst[1] = v1;
    }
    // stage B tile transposed: Bs[n][k] = bf16(W[k0+k][n0+n])
    #pragma unroll
    for (int s = t; s < 512; s += 256) {
      const int bk = s >> 4;          // 0..31
      const int bn = (s & 15) * 8;    // 0..120
      const float* wsrc = W + (size_t)(k0 + bk) * 1024 + n0 + bn;
      float4 f0 = *(const float4*)(wsrc);
      float4 f1 = *(const float4*)(wsrc + 4);
      Bs[(bn + 0) * 40 + bk] = f2bf(f0.x);
      Bs[(bn + 1) * 40 + bk] = f2bf(f0.y);
      Bs[(bn + 2) * 40 + bk] = f2bf(f0.z);
      Bs[(bn + 3) * 40 + bk] = f2bf(f0.w);
      Bs[(bn + 4) * 40 + bk] = f2bf(f1.x);
      Bs[(bn + 5) * 40 + bk] = f2bf(f1.y);
      Bs[(bn + 6) * 40 + bk] = f2bf(f1.z);
      Bs[(bn + 7) * 40 + bk] = f2bf(f1.w);
    }
    __syncthreads();

    bf16x8 af[4], bfr[4];
    #pragma unroll
    for (int i = 0; i < 4; i++)
      af[i] = *(const bf16x8*)(As + (wm * 64 + i * 16 + l15) * 32 + q4 * 8);
    #pragma unroll
    for (int j = 0; j < 4; j++)
      bfr[j] = *(const bf16x8*)(Bs + (wn * 64 + j * 16 + l15) * 40 + q4 * 8);
    #pragma unroll
    for (int i = 0; i < 4; i++)
      #pragma unroll
      for (int j = 0; j < 4; j++)
        acc[i][j] = __builtin_amdgcn_mfma_f32_16x16x32_bf16(af[i], bfr[j], acc[i][j], 0, 0, 0);
  }

  // epilogue: D[row=q4*4+r][col=l15] per 16x16 tile
  #pragma unroll
  for (int i = 0; i < 4; i++) {
    #pragma unroll
    for (int j = 0; j < 4; j++) {
      const int col = n0 + wn * 64 + j * 16 + l15;
      #pragma unroll
      for (int r = 0; r < 4; r++) {
        const int row = m0 + wm * 64 + i * 16 + q4 * 4 + r;
        if (C_F32) {
          ((float*)Cv)[(size_t)row * 1024 + col] = acc[i][j][r] * scale;
        } else {
          ((unsigned short*)Cv)[(size_t)row * 1024 + col] = f2bf(acc[i][j][r] * scale);
        }
      }
    }
  }
}

// ---------------------------------------------------------------------------
// Span kernel: per (chunk c, head h):
//   mq[d]      = max_r q[c][r][h][d]          (q already scaled)
//   spanK[d]   = max_r k[c][r][h][d]
//   w          = softmax_kk( mq . k[kk] )
//   spanV[f]   = sum_kk w[kk] * v[c][kk][h][f]
// block = 64 threads
// ---------------------------------------------------------------------------
__global__ __launch_bounds__(64) void span_kernel(
    const unsigned short* __restrict__ q,
    const unsigned short* __restrict__ k,
    const unsigned short* __restrict__ v,
    unsigned short* __restrict__ spanK,   // [256][16][64]
    unsigned short* __restrict__ spanV)   // [256][16][64]
{
  __shared__ unsigned short QS[64 * 66], KS[64 * 66], VS[64 * 66];
  __shared__ float mqs[64], ws[64];

  const int c = blockIdx.x;        // 0..255
  const int h = blockIdx.y;        // 0..15
  const int b = c >> 6, n = c & 63;
  const int t = threadIdx.x;       // 0..63

  const size_t rowbase = ((size_t)(b * LL + n * SEGC + t)) * 1024 + h * 64;
  #pragma unroll
  for (int j = 0; j < 4; j++) {
    g2lds16(QS + t * 66 + j * 16, q + rowbase + j * 16);
    g2lds16(KS + t * 66 + j * 16, k + rowbase + j * 16);
    g2lds16(VS + t * 66 + j * 16, v + rowbase + j * 16);
  }
  __syncthreads();

  // lane t = feature d
  float mq = -3.0e38f, sk = -3.0e38f;
  for (int r = 0; r < 64; r++) {
    mq = fmaxf(mq, bf2f(QS[r * 66 + t]));
    sk = fmaxf(sk, bf2f(KS[r * 66 + t]));
  }
  mqs[t] = mq;
  spanK[((size_t)c * 16 + h) * 64 + t] = f2bf(sk);
  __syncthreads();

  // lane t = key kk
  float logit = 0.f;
  for (int d = 0; d < 64; d++) logit += mqs[d] * bf2f(KS[t * 66 + d]);
  float m = logit;
  #pragma unroll
  for (int off = 32; off; off >>= 1) m = fmaxf(m, __shfl_xor(m, off, 64));
  float e = __expf(logit - m);
  float s = e;
  #pragma unroll
  for (int off = 32; off; off >>= 1) s += __shfl_xor(s, off, 64);
  ws[t] = e / s;
  __syncthreads();

  // lane t = feature f
  float sv = 0.f;
  for (int kk = 0; kk < 64; kk++) sv += ws[kk] * bf2f(VS[kk * 66 + t]);
  spanV[((size_t)c * 16 + h) * 64 + t] = f2bf(sv);
}

// ---------------------------------------------------------------------------
// Joint attention kernel: per (chunk c, head h), 256 threads (row=t>>2, p=t&3)
//  local logits (causal within segment) + prev logits (strictly previous
//  segments vs span_key), joint 128-way softmax, merged output.
// ---------------------------------------------------------------------------
__global__ __launch_bounds__(256) void attn_kernel(
    const unsigned short* __restrict__ q,
    const unsigned short* __restrict__ k,
    const unsigned short* __restrict__ v,
    const unsigned short* __restrict__ spanK,
    const unsigned short* __restrict__ spanV,
    unsigned short* __restrict__ att)
{
  // R1: phase A = QS | KS | SKS  (each [64][66] bf16)
  //     phase B = VS | SVS (reuse)
  __shared__ unsigned short R1[3 * 64 * 66];
  __shared__ float JW[64 * 129];           // joint logits then weights

  unsigned short* QS  = R1;
  unsigned short* KS  = R1 + 4224;
  unsigned short* SKS = R1 + 8448;
  unsigned short* VS  = R1;                // after phase 1
  unsigned short* SVS = R1 + 4224;

  const int c = blockIdx.x;          // 0..255
  const int h = blockIdx.y;          // 0..15
  const int b = c >> 6, n = c & 63;
  const int t = threadIdx.x;         // 0..255
  const int row = t >> 2;            // 0..63
  const int p   = t & 3;             // 0..3

  // phase 0: load QS, KS, SKS  (thread loads 16 bf16 of row rl each)
  const int rl = t >> 2;
  const int dp = (t & 3) * 16;
  const size_t qkbase = ((size_t)(b * LL + n * SEGC + rl)) * 1024 + h * 64 + dp;
  g2lds16(QS + rl * 66 + dp, q + qkbase);
  g2lds16(KS + rl * 66 + dp, k + qkbase);
  g2lds16(SKS + rl * 66 + dp, spanK + ((size_t)(b * 64 + rl) * 16 + h) * 64 + dp);
  __syncthreads();

  // phase 1: logits. Thread handles joint keys [p*32, p*32+32)
  float qf[64];
  {
    const unsigned int* qrow = (const unsigned int*)(QS + row * 66);
    #pragma unroll
    for (int i = 0; i < 32; i++) {
      unsigned int u = qrow[i];
      qf[2 * i]     = bflo(u);
      qf[2 * i + 1] = bfhi(u);
    }
  }
  {
    const unsigned short* kbase = (p < 2) ? KS : SKS;
    const bool isLocal = (p < 2);
    #pragma unroll 2
    for (int i = 0; i < 32; i++) {
      const int kr = (p & 1) * 32 + i;   // row within KS / SKS
      const unsigned int* krow = (const unsigned int*)(kbase + kr * 66);
      float acc = 0.f;
      #pragma unroll
      for (int d2 = 0; d2 < 32; d2++) {
        unsigned int u = krow[d2];
        acc += qf[2 * d2]     * bflo(u);
        acc += qf[2 * d2 + 1] * bfhi(u);
      }
      const bool valid = isLocal ? (kr <= row) : (kr < n);
      JW[row * 129 + p * 32 + i] = valid ? acc : NEGV;
    }
  }
  __syncthreads();   // (1) phase 1 done: JW complete, R1 free

  // phase 1.5: load V and spanV into R1 (overwrites QS/KS)
  g2lds16(VS + rl * 66 + dp, v + qkbase);
  g2lds16(SVS + rl * 66 + dp, spanV + ((size_t)(b * 64 + rl) * 16 + h) * 64 + dp);

  // phase 2a: row softmax stats (reads JW only)
  float mrow = -3.0e38f;
  {
    const float* jr = JW + row * 129;
    for (int key = 0; key < 128; key++) mrow = fmaxf(mrow, jr[key]);
  }
  float ssum = 0.f;
  {
    const float* jr = JW + row * 129;
    for (int key = 0; key < 128; key++) ssum += __expf(jr[key] - mrow);
  }
  const float inv = 1.0f / ssum;
  __syncthreads();   // (2) stats read done + V LDS writes done

  // phase 2b: overwrite own slice of JW with weights
  #pragma unroll 4
  for (int i = 0; i < 32; i++) {
    const int kj = row * 129 + p * 32 + i;
    JW[kj] = __expf(JW[kj] - mrow) * inv;
  }
  __syncthreads();   // (3)

  // phase 3: merged[f] = sum_{kk<64} w*V[kk][f] + sum_j w*SV[j][f]
  // thread covers f in [p*16, p*16+16)
  float acc[16];
  #pragma unroll
  for (int i = 0; i < 16; i++) acc[i] = 0.f;
  const int fb = p * 16;
  #pragma unroll 2
  for (int key = 0; key < 128; key++) {
    const float w = JW[row * 129 + key];
    const unsigned short* vrow = (key < 64) ? (VS + key * 66) : (SVS + (key - 64) * 66);
    const unsigned int* vp = (const unsigned int*)(vrow + fb);
    #pragma unroll
    for (int d2 = 0; d2 < 8; d2++) {
      unsigned int u = vp[d2];
      acc[2 * d2]     += w * bflo(u);
      acc[2 * d2 + 1] += w * bfhi(u);
    }
  }

  // store 16 bf16 (32B) contiguous
  int4 ov[2];
  unsigned short* os = (unsigned short*)ov;
  #pragma unroll
  for (int i = 0; i < 16; i++) os[i] = f2bf(acc[i]);
  int4* dst = (int4*)(att + ((size_t)(b * LL + n * SEGC + row)) * 1024 + h * 64 + fb);
  dst[0] = ov[0];
  dst[1] = ov[1];
}

// ---------------------------------------------------------------------------
extern "C" void kernel_launch(void* const* d_in, const int* in_sizes, int n_in,
                              void* d_out, int out_size, void* d_ws, size_t ws_size,
                              hipStream_t stream) {
  const float* x  = (const float*)d_in[0];  // [B][L][DM] f32
  const float* wq = (const float*)d_in[1];  // [DM][H][HD] f32
  const float* wk = (const float*)d_in[2];
  const float* wv = (const float*)d_in[3];
  const float* wo = (const float*)d_in[4];  // [H][HD][DM] f32
  float* out = (float*)d_out;               // [B][L][DM] f32

  unsigned short* wsp  = (unsigned short*)d_ws;
  unsigned short* qb   = wsp;                   // 16777216 bf16
  unsigned short* kb   = qb + 16777216;
  unsigned short* vb   = kb + 16777216;
  unsigned short* attb = vb + 16777216;
  unsigned short* skb  = attb + 16777216;       // 262144
  unsigned short* svb  = skb + 262144;          // 262144
  // total ws use: ~135 MB

  const dim3 gg(128, 8, 1);
  // q pre-scaled by 1/sqrt(HD) = 0.125
  gemm_k<true, false><<<gg, 256, 0, stream>>>((const void*)x, wq, (void*)qb, 0.125f);
  gemm_k<true, false><<<gg, 256, 0, stream>>>((const void*)x, wk, (void*)kb, 1.0f);
  gemm_k<true, false><<<gg, 256, 0, stream>>>((const void*)x, wv, (void*)vb, 1.0f);
  span_kernel<<<dim3(256, 16), 64, 0, stream>>>(qb, kb, vb, skb, svb);
  attn_kernel<<<dim3(256, 16), 256, 0, stream>>>(qb, kb, vb, skb, svb, attb);
  gemm_k<false, true><<<gg, 256, 0, stream>>>((const void*)attb, wo, (void*)out, 1.0f);
}

// Round 3
// 853.819 us; speedup vs baseline: 1.3675x; 1.3675x over previous
//
#include <hip/hip_runtime.h>

// Problem constants
#define BB    4
#define LL    4096
#define DM    1024
#define HH    16
#define SEGC  64
#define HDC   64
#define NSEGC 64
#define NEGV  -1.0e10f

typedef __bf16 bf16x8 __attribute__((ext_vector_type(8)));
typedef float  f32x4  __attribute__((ext_vector_type(4)));

__device__ __forceinline__ float bflo(unsigned int u) {
  union { unsigned int u; float f; } x; x.u = u << 16; return x.f;
}
__device__ __forceinline__ float bfhi(unsigned int u) {
  union { unsigned int u; float f; } x; x.u = u & 0xffff0000u; return x.f;
}
__device__ __forceinline__ float bf2f(unsigned short s) {
  union { unsigned int u; float f; } x; x.u = ((unsigned int)s) << 16; return x.f;
}
__device__ __forceinline__ unsigned short f2bf(float f) {
  union { float f; unsigned int u; } x; x.f = f;
  unsigned int u = x.u;
  return (unsigned short)((u + 0x7fffu + ((u >> 16) & 1u)) >> 16);
}

// copy 16 bf16 from global (16B-aligned) to LDS (4B-aligned)
__device__ __forceinline__ void g2lds16(unsigned short* dst, const unsigned short* src) {
  int4 a = *(const int4*)(src);
  int4 b = *(const int4*)(src + 8);
  unsigned int* d = (unsigned int*)dst;
  const unsigned int* pa = (const unsigned int*)&a;
  const unsigned int* pb = (const unsigned int*)&b;
  d[0]=pa[0]; d[1]=pa[1]; d[2]=pa[2]; d[3]=pa[3];
  d[4]=pb[0]; d[5]=pb[1]; d[6]=pb[2]; d[7]=pb[3];
}

// ---------------------------------------------------------------------------
// Generic GEMM: C[M x 1024] = scale * (A[M x 1024] @ W[1024 x 1024])
// A: f32 or bf16 (template). W: f32 (converted to bf16 in staging).
// C: f32 or bf16 (template). 128x128 tile, BK=32, 4 waves (2x2), each wave
// 4x4 of 16x16x32 bf16 MFMA, fp32 accumulate.
// ---------------------------------------------------------------------------
template <bool A_F32, bool C_F32>
__global__ __launch_bounds__(256) void gemm_k(
    const void* __restrict__ Av,
    const float* __restrict__ W,
    void* __restrict__ Cv,
    float scale)
{
  __shared__ unsigned short As[128 * 32];   // [m][k], stride 32
  __shared__ unsigned short Bs[128 * 40];   // [n][k], stride 40 (16B-aligned rows)

  const int t    = threadIdx.x;
  const int wave = t >> 6;
  const int lane = t & 63;
  const int l15  = lane & 15;
  const int q4   = lane >> 4;
  const int wm   = wave >> 1;
  const int wn   = wave & 1;
  const int m0   = blockIdx.x * 128;
  const int n0   = blockIdx.y * 128;

  f32x4 acc[4][4];
  #pragma unroll
  for (int i = 0; i < 4; i++)
    #pragma unroll
    for (int j = 0; j < 4; j++)
      acc[i][j] = (f32x4){0.f, 0.f, 0.f, 0.f};

  const int am = t >> 1;            // 0..127
  const int ak = (t & 1) * 16;      // 0 / 16

  for (int k0 = 0; k0 < 1024; k0 += 32) {
    __syncthreads();
    // stage A tile [128][32] as bf16
    if (A_F32) {
      const float* src = (const float*)Av + (size_t)(m0 + am) * 1024 + k0 + ak;
      unsigned short tmp[16];
      #pragma unroll
      for (int i = 0; i < 4; i++) {
        float4 f = *(const float4*)(src + i * 4);
        tmp[4 * i + 0] = f2bf(f.x);
        tmp[4 * i + 1] = f2bf(f.y);
        tmp[4 * i + 2] = f2bf(f.z);
        tmp[4 * i + 3] = f2bf(f.w);
      }
      int4* dst = (int4*)(As + am * 32 + ak);
      dst[0] = ((const int4*)tmp)[0];
      dst[1] = ((const int4*)tmp)[1];
    } else {
      const unsigned short* src = (const unsigned short*)Av + (size_t)(m0 + am) * 1024 + k0 + ak;
      int4 v0 = *(const int4*)(src);
      int4 v1 = *(const int4*)(src + 8);
      int4* dst = (int4*)(As + am * 32 + ak);
      dst[0] = v0; dst[1] = v1;
    }
    // stage B tile transposed: Bs[n][k] = bf16(W[k0+k][n0+n])
    #pragma unroll
    for (int s = t; s < 512; s += 256) {
      const int bk = s >> 4;          // 0..31
      const int bn = (s & 15) * 8;    // 0..120
      const float* wsrc = W + (size_t)(k0 + bk) * 1024 + n0 + bn;
      float4 f0 = *(const float4*)(wsrc);
      float4 f1 = *(const float4*)(wsrc + 4);
      Bs[(bn + 0) * 40 + bk] = f2bf(f0.x);
      Bs[(bn + 1) * 40 + bk] = f2bf(f0.y);
      Bs[(bn + 2) * 40 + bk] = f2bf(f0.z);
      Bs[(bn + 3) * 40 + bk] = f2bf(f0.w);
      Bs[(bn + 4) * 40 + bk] = f2bf(f1.x);
      Bs[(bn + 5) * 40 + bk] = f2bf(f1.y);
      Bs[(bn + 6) * 40 + bk] = f2bf(f1.z);
      Bs[(bn + 7) * 40 + bk] = f2bf(f1.w);
    }
    __syncthreads();

    bf16x8 af[4], bfr[4];
    #pragma unroll
    for (int i = 0; i < 4; i++)
      af[i] = *(const bf16x8*)(As + (wm * 64 + i * 16 + l15) * 32 + q4 * 8);
    #pragma unroll
    for (int j = 0; j < 4; j++)
      bfr[j] = *(const bf16x8*)(Bs + (wn * 64 + j * 16 + l15) * 40 + q4 * 8);
    #pragma unroll
    for (int i = 0; i < 4; i++)
      #pragma unroll
      for (int j = 0; j < 4; j++)
        acc[i][j] = __builtin_amdgcn_mfma_f32_16x16x32_bf16(af[i], bfr[j], acc[i][j], 0, 0, 0);
  }

  // epilogue: D[row=q4*4+r][col=l15] per 16x16 tile
  #pragma unroll
  for (int i = 0; i < 4; i++) {
    #pragma unroll
    for (int j = 0; j < 4; j++) {
      const int col = n0 + wn * 64 + j * 16 + l15;
      #pragma unroll
      for (int r = 0; r < 4; r++) {
        const int row = m0 + wm * 64 + i * 16 + q4 * 4 + r;
        if (C_F32) {
          ((float*)Cv)[(size_t)row * 1024 + col] = acc[i][j][r] * scale;
        } else {
          ((unsigned short*)Cv)[(size_t)row * 1024 + col] = f2bf(acc[i][j][r] * scale);
        }
      }
    }
  }
}

// ---------------------------------------------------------------------------
// Span kernel: per (chunk c, head h):
//   mq[d]    = max_r q[c][r][h][d]          (q already scaled)
//   spanK[d] = max_r k[c][r][h][d]
//   w        = softmax_kk( mq . k[kk] )
//   spanV[f] = sum_kk w[kk] * v[c][kk][h][f]
// ---------------------------------------------------------------------------
__global__ __launch_bounds__(64) void span_kernel(
    const unsigned short* __restrict__ q,
    const unsigned short* __restrict__ k,
    const unsigned short* __restrict__ v,
    unsigned short* __restrict__ spanK,   // [256][16][64]
    unsigned short* __restrict__ spanV)   // [256][16][64]
{
  __shared__ unsigned short QS[64 * 66], KS[64 * 66], VS[64 * 66];
  __shared__ float mqs[64], ws[64];

  const int c = blockIdx.x;        // 0..255
  const int h = blockIdx.y;        // 0..15
  const int b = c >> 6, n = c & 63;
  const int t = threadIdx.x;       // 0..63

  const size_t rowbase = ((size_t)(b * LL + n * SEGC + t)) * 1024 + h * 64;
  #pragma unroll
  for (int j = 0; j < 4; j++) {
    g2lds16(QS + t * 66 + j * 16, q + rowbase + j * 16);
    g2lds16(KS + t * 66 + j * 16, k + rowbase + j * 16);
    g2lds16(VS + t * 66 + j * 16, v + rowbase + j * 16);
  }
  __syncthreads();

  // lane t = feature d
  float mq = -3.0e38f, sk = -3.0e38f;
  for (int r = 0; r < 64; r++) {
    mq = fmaxf(mq, bf2f(QS[r * 66 + t]));
    sk = fmaxf(sk, bf2f(KS[r * 66 + t]));
  }
  mqs[t] = mq;
  spanK[((size_t)c * 16 + h) * 64 + t] = f2bf(sk);
  __syncthreads();

  // lane t = key kk
  float logit = 0.f;
  for (int d = 0; d < 64; d++) logit += mqs[d] * bf2f(KS[t * 66 + d]);
  float m = logit;
  #pragma unroll
  for (int off = 32; off; off >>= 1) m = fmaxf(m, __shfl_xor(m, off, 64));
  float e = __expf(logit - m);
  float s = e;
  #pragma unroll
  for (int off = 32; off; off >>= 1) s += __shfl_xor(s, off, 64);
  ws[t] = e / s;
  __syncthreads();

  // lane t = feature f
  float sv = 0.f;
  for (int kk = 0; kk < 64; kk++) sv += ws[kk] * bf2f(VS[kk * 66 + t]);
  spanV[((size_t)c * 16 + h) * 64 + t] = f2bf(sv);
}

// ---------------------------------------------------------------------------
// Joint attention kernel (MFMA version): per (chunk c, head h), 4 waves.
// Wave w owns att rows 16w..16w+15:
//   logits  = Q[16x64] @ concat(K,spanK)^T[128x64]   (8 col-tiles, K=64)
//   softmax   wave-private (shuffle over 16-lane groups)
//   merged  = W[16x128] @ concat(V,spanV)[128x64]    (4 col-tiles, K=128)
// Fragments of Q/K/spanK loaded directly from global in MFMA layout.
// W and V' round-trip through LDS (stride 136 -> 2-way conflicts only).
// ---------------------------------------------------------------------------
__global__ __launch_bounds__(256) void attn_kernel(
    const unsigned short* __restrict__ q,
    const unsigned short* __restrict__ k,
    const unsigned short* __restrict__ v,
    const unsigned short* __restrict__ spanK,
    const unsigned short* __restrict__ spanV,
    unsigned short* __restrict__ att)
{
  __shared__ unsigned short VT[64 * 136];  // [f][k'], k' = 0..127 joint key
  __shared__ unsigned short WL[64 * 136];  // [att row][k'] weights (bf16)

  const int c = blockIdx.x;          // 0..255
  const int h = blockIdx.y;          // 0..15
  const int b = c >> 6, n = c & 63;
  const int t = threadIdx.x;         // 0..255
  const int wave = t >> 6;
  const int lane = t & 63;
  const int l15  = lane & 15;
  const int q4   = lane >> 4;

  // ---- phase 0: stage V' = concat(V, spanV) transposed into VT[f][k'] ----
  #pragma unroll
  for (int it = 0; it < 4; it++) {
    const int idx = t + 256 * it;       // 0..1023
    const int kp  = idx >> 3;           // joint key row 0..127
    const int fc  = (idx & 7) * 8;      // feature col base
    const unsigned short* src;
    if (kp < 64)
      src = v + ((size_t)(b * LL + n * SEGC + kp)) * 1024 + h * 64 + fc;
    else
      src = spanV + ((size_t)(b * 64 + (kp - 64)) * 16 + h) * 64 + fc;
    int4 val = *(const int4*)src;
    const unsigned short* e = (const unsigned short*)&val;
    #pragma unroll
    for (int i = 0; i < 8; i++) VT[(fc + i) * 136 + kp] = e[i];
  }

  // ---- logits: Q @ K'^T via MFMA, fragments direct from global ----
  // A-frag: rows 16*wave + l15, k = 32s + 8*q4
  bf16x8 af[2];
  {
    const size_t qbase = ((size_t)(b * LL + n * SEGC + wave * 16 + l15)) * 1024
                         + h * 64 + q4 * 8;
    af[0] = *(const bf16x8*)(q + qbase);
    af[1] = *(const bf16x8*)(q + qbase + 32);
  }

  f32x4 accl[8];
  #pragma unroll
  for (int tt = 0; tt < 8; tt++) accl[tt] = (f32x4){0.f, 0.f, 0.f, 0.f};

  #pragma unroll
  for (int s = 0; s < 2; s++) {
    bf16x8 bfr[8];
    #pragma unroll
    for (int tt = 0; tt < 8; tt++) {
      const unsigned short* src;
      if (tt < 4)
        src = k + ((size_t)(b * LL + n * SEGC + tt * 16 + l15)) * 1024
              + h * 64 + s * 32 + q4 * 8;
      else
        src = spanK + ((size_t)((b * 64 + (tt - 4) * 16 + l15) * 16 + h)) * 64
              + s * 32 + q4 * 8;
      bfr[tt] = *(const bf16x8*)src;
    }
    #pragma unroll
    for (int tt = 0; tt < 8; tt++)
      accl[tt] = __builtin_amdgcn_mfma_f32_16x16x32_bf16(af[s], bfr[tt], accl[tt], 0, 0, 0);
  }

  // ---- mask ----
  #pragma unroll
  for (int tt = 0; tt < 8; tt++) {
    const int col = (tt & 3) * 16 + l15;   // local col (tt<4) or span idx (tt>=4)
    #pragma unroll
    for (int rr = 0; rr < 4; rr++) {
      const int r_att = wave * 16 + q4 * 4 + rr;
      const bool valid = (tt < 4) ? (col <= r_att) : (col < n);
      if (!valid) accl[tt][rr] = NEGV;
    }
  }

  // ---- wave-private row softmax; weights -> WL (bf16) ----
  #pragma unroll
  for (int rr = 0; rr < 4; rr++) {
    float mx = accl[0][rr];
    #pragma unroll
    for (int tt = 1; tt < 8; tt++) mx = fmaxf(mx, accl[tt][rr]);
    #pragma unroll
    for (int msk = 1; msk < 16; msk <<= 1) mx = fmaxf(mx, __shfl_xor(mx, msk, 64));
    float sm = 0.f;
    float ex[8];
    #pragma unroll
    for (int tt = 0; tt < 8; tt++) { ex[tt] = __expf(accl[tt][rr] - mx); sm += ex[tt]; }
    #pragma unroll
    for (int msk = 1; msk < 16; msk <<= 1) sm += __shfl_xor(sm, msk, 64);
    const float inv = 1.0f / sm;
    const int r_att = wave * 16 + q4 * 4 + rr;
    #pragma unroll
    for (int tt = 0; tt < 8; tt++) {
      const int colj = (tt < 4) ? (tt * 16 + l15) : (64 + (tt - 4) * 16 + l15);
      WL[r_att * 136 + colj] = f2bf(ex[tt] * inv);
    }
  }

  __syncthreads();   // VT staged by all; WL rows are wave-private

  // ---- merged = W[16x128] @ V'[128x64] per wave ----
  f32x4 accm[4];
  #pragma unroll
  for (int j = 0; j < 4; j++) accm[j] = (f32x4){0.f, 0.f, 0.f, 0.f};
  #pragma unroll
  for (int s = 0; s < 4; s++) {
    const bf16x8 aw = *(const bf16x8*)(WL + (wave * 16 + l15) * 136 + s * 32 + q4 * 8);
    #pragma unroll
    for (int j = 0; j < 4; j++) {
      const bf16x8 bv = *(const bf16x8*)(VT + (j * 16 + l15) * 136 + s * 32 + q4 * 8);
      accm[j] = __builtin_amdgcn_mfma_f32_16x16x32_bf16(aw, bv, accm[j], 0, 0, 0);
    }
  }

  // ---- epilogue ----
  #pragma unroll
  for (int j = 0; j < 4; j++) {
    #pragma unroll
    for (int rr = 0; rr < 4; rr++) {
      const int row = wave * 16 + q4 * 4 + rr;
      const int col = j * 16 + l15;
      att[((size_t)(b * LL + n * SEGC + row)) * 1024 + h * 64 + col] = f2bf(accm[j][rr]);
    }
  }
}

// ---------------------------------------------------------------------------
extern "C" void kernel_launch(void* const* d_in, const int* in_sizes, int n_in,
                              void* d_out, int out_size, void* d_ws, size_t ws_size,
                              hipStream_t stream) {
  const float* x  = (const float*)d_in[0];  // [B][L][DM] f32
  const float* wq = (const float*)d_in[1];  // [DM][H][HD] f32
  const float* wk = (const float*)d_in[2];
  const float* wv = (const float*)d_in[3];
  const float* wo = (const float*)d_in[4];  // [H][HD][DM] f32
  float* out = (float*)d_out;               // [B][L][DM] f32

  unsigned short* wsp  = (unsigned short*)d_ws;
  unsigned short* qb   = wsp;                   // 16777216 bf16
  unsigned short* kb   = qb + 16777216;
  unsigned short* vb   = kb + 16777216;
  unsigned short* attb = vb + 16777216;
  unsigned short* skb  = attb + 16777216;       // 262144
  unsigned short* svb  = skb + 262144;          // 262144
  // total ws use: ~135 MB

  const dim3 gg(128, 8, 1);
  // q pre-scaled by 1/sqrt(HD) = 0.125
  gemm_k<true, false><<<gg, 256, 0, stream>>>((const void*)x, wq, (void*)qb, 0.125f);
  gemm_k<true, false><<<gg, 256, 0, stream>>>((const void*)x, wk, (void*)kb, 1.0f);
  gemm_k<true, false><<<gg, 256, 0, stream>>>((const void*)x, wv, (void*)vb, 1.0f);
  span_kernel<<<dim3(256, 16), 64, 0, stream>>>(qb, kb, vb, skb, svb);
  attn_kernel<<<dim3(256, 16), 256, 0, stream>>>(qb, kb, vb, skb, svb, attb);
  gemm_k<false, true><<<gg, 256, 0, stream>>>((const void*)attb, wo, (void*)out, 1.0f);
}

// Round 4
// 556.778 us; speedup vs baseline: 2.0971x; 1.5335x over previous
//
#include <hip/hip_runtime.h>

// Problem constants
#define BB    4
#define LL    4096
#define DM    1024
#define HH    16
#define SEGC  64
#define HDC   64
#define NSEGC 64
#define NEGV  -1.0e10f

typedef __bf16 bf16x8 __attribute__((ext_vector_type(8)));
typedef float  f32x4  __attribute__((ext_vector_type(4)));

__device__ __forceinline__ float bf2f(unsigned short s) {
  union { unsigned int u; float f; } x; x.u = ((unsigned int)s) << 16; return x.f;
}
__device__ __forceinline__ unsigned short f2bf(float f) {
  union { float f; unsigned int u; } x; x.f = f;
  unsigned int u = x.u;
  return (unsigned short)((u + 0x7fffu + ((u >> 16) & 1u)) >> 16);
}

// async global->LDS, 16 bytes per lane; LDS dest must be wave-uniform base,
// lane i lands at l + i*16 bytes.
__device__ __forceinline__ void gl2lds16(const unsigned short* g, unsigned short* l) {
  __builtin_amdgcn_global_load_lds(
      (const __attribute__((address_space(1))) unsigned int*)g,
      (__attribute__((address_space(3))) unsigned int*)l,
      16, 0, 0);
}

// copy 16 bf16 from global (16B-aligned) to LDS (4B-aligned) via VGPR
__device__ __forceinline__ void g2lds16(unsigned short* dst, const unsigned short* src) {
  int4 a = *(const int4*)(src);
  int4 b = *(const int4*)(src + 8);
  unsigned int* d = (unsigned int*)dst;
  const unsigned int* pa = (const unsigned int*)&a;
  const unsigned int* pb = (const unsigned int*)&b;
  d[0]=pa[0]; d[1]=pa[1]; d[2]=pa[2]; d[3]=pa[3];
  d[4]=pb[0]; d[5]=pb[1]; d[6]=pb[2]; d[7]=pb[3];
}

// ---------------------------------------------------------------------------
// cvt_x: f32 -> bf16, 8 elems/thread
// ---------------------------------------------------------------------------
__global__ __launch_bounds__(256) void cvt_x(const float* __restrict__ x,
                                             unsigned short* __restrict__ xb) {
  const size_t i = ((size_t)blockIdx.x * 256 + threadIdx.x) * 8;
  float4 a = *(const float4*)(x + i);
  float4 b = *(const float4*)(x + i + 4);
  unsigned short o[8];
  o[0]=f2bf(a.x); o[1]=f2bf(a.y); o[2]=f2bf(a.z); o[3]=f2bf(a.w);
  o[4]=f2bf(b.x); o[5]=f2bf(b.y); o[6]=f2bf(b.z); o[7]=f2bf(b.w);
  *(int4*)(xb + i) = *(const int4*)o;
}

// ---------------------------------------------------------------------------
// pack_w: build WqkvT [3072][1024] bf16 (q cols pre-scaled by 0.125) and
// woT [1024][1024] bf16, both transposed to [N][K] for the GEMM.
// grid 16 x 256: blocks 0..11 -> WqkvT, 12..15 -> woT.
// Per k, a wave reads 64 consecutive cols of one source row -> coalesced.
// ---------------------------------------------------------------------------
__global__ __launch_bounds__(256) void pack_w(
    const float* __restrict__ wq, const float* __restrict__ wk,
    const float* __restrict__ wv, const float* __restrict__ wo,
    unsigned short* __restrict__ WqkvT, unsigned short* __restrict__ woT) {
  const int bid = blockIdx.x;
  const int t = threadIdx.x;
  const float* src;
  unsigned short* dst;
  int col; float scale = 1.0f;
  if (bid < 12) {
    const int n = bid * 256 + t;          // 0..3071
    col = n & 1023;
    if (n < 1024)      { src = wq; scale = 0.125f; }
    else if (n < 2048) { src = wk; }
    else               { src = wv; }
    dst = WqkvT + (size_t)n * 1024;
  } else {
    const int n = (bid - 12) * 256 + t;   // 0..1023
    col = n;
    src = wo;
    dst = woT + (size_t)n * 1024;
  }
  for (int k = 0; k < 1024; k += 8) {
    unsigned short o[8];
    #pragma unroll
    for (int j = 0; j < 8; j++)
      o[j] = f2bf(src[(size_t)(k + j) * 1024 + col] * scale);
    *(int4*)(dst + k) = *(const int4*)o;
  }
}

// ---------------------------------------------------------------------------
// GEMM: C[M x N] = A[M x 1024] @ Bt[N x 1024]^T    (bf16 in, fp32 accum)
// m97 structure: 128x128 tile, BK=32, global_load_lds width=16 staging,
// 4 waves (2x2), each wave 4x4 of 16x16x32 bf16 MFMA.
// ---------------------------------------------------------------------------
template <bool C_F32>
__global__ __launch_bounds__(256) void gemm_bt(
    const unsigned short* __restrict__ A,
    const unsigned short* __restrict__ Bt,
    void* __restrict__ Cv,
    int ldc)
{
  __shared__ __align__(16) unsigned short As[128 * 32];  // [m][k]
  __shared__ __align__(16) unsigned short Bs[128 * 32];  // [n][k]

  const int t    = threadIdx.x;
  const int wave = t >> 6;
  const int lane = t & 63;
  const int l15  = lane & 15;
  const int q4   = lane >> 4;
  const int wm   = wave >> 1;
  const int wn   = wave & 1;
  const int m0   = blockIdx.x * 128;
  const int n0   = blockIdx.y * 128;

  // staging geometry: one global_load_lds issue = 64 lanes x 16B = 1024B
  // = 16 rows of 64B. lane -> row = lane>>2, col8 = (lane&3)*8.
  const int srow = lane >> 2;
  const int scol = (lane & 3) * 8;

  f32x4 acc[4][4];
  #pragma unroll
  for (int i = 0; i < 4; i++)
    #pragma unroll
    for (int j = 0; j < 4; j++)
      acc[i][j] = (f32x4){0.f, 0.f, 0.f, 0.f};

  for (int k0 = 0; k0 < 1024; k0 += 32) {
    __syncthreads();   // previous compute done reading LDS
    #pragma unroll
    for (int i = 0; i < 2; i++) {
      const int c = wave * 2 + i;        // chunk 0..7 (16 rows each)
      gl2lds16(A  + (size_t)(m0 + c * 16 + srow) * 1024 + k0 + scol, As + c * 512);
      gl2lds16(Bt + (size_t)(n0 + c * 16 + srow) * 1024 + k0 + scol, Bs + c * 512);
    }
    __syncthreads();   // staging drained (compiler emits vmcnt(0) before barrier)

    bf16x8 af[4], bfr[4];
    #pragma unroll
    for (int i = 0; i < 4; i++)
      af[i] = *(const bf16x8*)(As + (wm * 64 + i * 16 + l15) * 32 + q4 * 8);
    #pragma unroll
    for (int j = 0; j < 4; j++)
      bfr[j] = *(const bf16x8*)(Bs + (wn * 64 + j * 16 + l15) * 32 + q4 * 8);
    #pragma unroll
    for (int i = 0; i < 4; i++)
      #pragma unroll
      for (int j = 0; j < 4; j++)
        acc[i][j] = __builtin_amdgcn_mfma_f32_16x16x32_bf16(af[i], bfr[j], acc[i][j], 0, 0, 0);
  }

  // epilogue: D[row=q4*4+r][col=l15] per 16x16 tile
  #pragma unroll
  for (int i = 0; i < 4; i++) {
    #pragma unroll
    for (int j = 0; j < 4; j++) {
      const int col = n0 + wn * 64 + j * 16 + l15;
      #pragma unroll
      for (int r = 0; r < 4; r++) {
        const int row = m0 + wm * 64 + i * 16 + q4 * 4 + r;
        if (C_F32) ((float*)Cv)[(size_t)row * ldc + col] = acc[i][j][r];
        else ((unsigned short*)Cv)[(size_t)row * ldc + col] = f2bf(acc[i][j][r]);
      }
    }
  }
}

// ---------------------------------------------------------------------------
// Span kernel: per (chunk c, head h). qkv strided [row][3072]: q|k|v.
// ---------------------------------------------------------------------------
__global__ __launch_bounds__(64) void span_kernel(
    const unsigned short* __restrict__ qkv,
    unsigned short* __restrict__ spanK,   // [256][16][64]
    unsigned short* __restrict__ spanV)   // [256][16][64]
{
  __shared__ unsigned short QS[64 * 66], KS[64 * 66], VS[64 * 66];
  __shared__ float mqs[64], ws[64];

  const int c = blockIdx.x;        // 0..255
  const int h = blockIdx.y;        // 0..15
  const int b = c >> 6, n = c & 63;
  const int t = threadIdx.x;       // 0..63

  const size_t rowbase = ((size_t)(b * LL + n * SEGC + t)) * 3072 + h * 64;
  #pragma unroll
  for (int j = 0; j < 4; j++) {
    g2lds16(QS + t * 66 + j * 16, qkv + rowbase + j * 16);
    g2lds16(KS + t * 66 + j * 16, qkv + rowbase + 1024 + j * 16);
    g2lds16(VS + t * 66 + j * 16, qkv + rowbase + 2048 + j * 16);
  }
  __syncthreads();

  float mq = -3.0e38f, sk = -3.0e38f;
  for (int r = 0; r < 64; r++) {
    mq = fmaxf(mq, bf2f(QS[r * 66 + t]));
    sk = fmaxf(sk, bf2f(KS[r * 66 + t]));
  }
  mqs[t] = mq;
  spanK[((size_t)c * 16 + h) * 64 + t] = f2bf(sk);
  __syncthreads();

  float logit = 0.f;
  for (int d = 0; d < 64; d++) logit += mqs[d] * bf2f(KS[t * 66 + d]);
  float m = logit;
  #pragma unroll
  for (int off = 32; off; off >>= 1) m = fmaxf(m, __shfl_xor(m, off, 64));
  float e = __expf(logit - m);
  float s = e;
  #pragma unroll
  for (int off = 32; off; off >>= 1) s += __shfl_xor(s, off, 64);
  ws[t] = e / s;
  __syncthreads();

  float sv = 0.f;
  for (int kk = 0; kk < 64; kk++) sv += ws[kk] * bf2f(VS[kk * 66 + t]);
  spanV[((size_t)c * 16 + h) * 64 + t] = f2bf(sv);
}

// ---------------------------------------------------------------------------
// Joint attention kernel (MFMA): per (chunk c, head h), 4 waves.
// ---------------------------------------------------------------------------
__global__ __launch_bounds__(256) void attn_kernel(
    const unsigned short* __restrict__ qkv,
    const unsigned short* __restrict__ spanK,
    const unsigned short* __restrict__ spanV,
    unsigned short* __restrict__ att)
{
  __shared__ unsigned short VT[64 * 136];  // [f][k'], k' = joint key 0..127
  __shared__ unsigned short WL[64 * 136];  // [att row][k'] weights (bf16)

  const int c = blockIdx.x;          // 0..255
  const int h = blockIdx.y;          // 0..15
  const int b = c >> 6, n = c & 63;
  const int t = threadIdx.x;
  const int wave = t >> 6;
  const int lane = t & 63;
  const int l15  = lane & 15;
  const int q4   = lane >> 4;

  // stage V' = concat(V, spanV) transposed into VT[f][k']
  #pragma unroll
  for (int it = 0; it < 4; it++) {
    const int idx = t + 256 * it;       // 0..1023
    const int kp  = idx >> 3;           // joint key 0..127
    const int fc  = (idx & 7) * 8;
    const unsigned short* src;
    if (kp < 64)
      src = qkv + ((size_t)(b * LL + n * SEGC + kp)) * 3072 + 2048 + h * 64 + fc;
    else
      src = spanV + ((size_t)(b * 64 + (kp - 64)) * 16 + h) * 64 + fc;
    int4 val = *(const int4*)src;
    const unsigned short* e = (const unsigned short*)&val;
    #pragma unroll
    for (int i = 0; i < 8; i++) VT[(fc + i) * 136 + kp] = e[i];
  }

  // logits: Q @ K'^T via MFMA, fragments direct from global
  bf16x8 af[2];
  {
    const size_t qbase = ((size_t)(b * LL + n * SEGC + wave * 16 + l15)) * 3072
                         + h * 64 + q4 * 8;
    af[0] = *(const bf16x8*)(qkv + qbase);
    af[1] = *(const bf16x8*)(qkv + qbase + 32);
  }

  f32x4 accl[8];
  #pragma unroll
  for (int tt = 0; tt < 8; tt++) accl[tt] = (f32x4){0.f, 0.f, 0.f, 0.f};

  #pragma unroll
  for (int s = 0; s < 2; s++) {
    bf16x8 bfr[8];
    #pragma unroll
    for (int tt = 0; tt < 8; tt++) {
      const unsigned short* src;
      if (tt < 4)
        src = qkv + ((size_t)(b * LL + n * SEGC + tt * 16 + l15)) * 3072
              + 1024 + h * 64 + s * 32 + q4 * 8;
      else
        src = spanK + ((size_t)((b * 64 + (tt - 4) * 16 + l15) * 16 + h)) * 64
              + s * 32 + q4 * 8;
      bfr[tt] = *(const bf16x8*)src;
    }
    #pragma unroll
    for (int tt = 0; tt < 8; tt++)
      accl[tt] = __builtin_amdgcn_mfma_f32_16x16x32_bf16(af[s], bfr[tt], accl[tt], 0, 0, 0);
  }

  // mask
  #pragma unroll
  for (int tt = 0; tt < 8; tt++) {
    const int col = (tt & 3) * 16 + l15;
    #pragma unroll
    for (int rr = 0; rr < 4; rr++) {
      const int r_att = wave * 16 + q4 * 4 + rr;
      const bool valid = (tt < 4) ? (col <= r_att) : (col < n);
      if (!valid) accl[tt][rr] = NEGV;
    }
  }

  // wave-private row softmax; weights -> WL (bf16)
  #pragma unroll
  for (int rr = 0; rr < 4; rr++) {
    float mx = accl[0][rr];
    #pragma unroll
    for (int tt = 1; tt < 8; tt++) mx = fmaxf(mx, accl[tt][rr]);
    #pragma unroll
    for (int msk = 1; msk < 16; msk <<= 1) mx = fmaxf(mx, __shfl_xor(mx, msk, 64));
    float sm = 0.f;
    float ex[8];
    #pragma unroll
    for (int tt = 0; tt < 8; tt++) { ex[tt] = __expf(accl[tt][rr] - mx); sm += ex[tt]; }
    #pragma unroll
    for (int msk = 1; msk < 16; msk <<= 1) sm += __shfl_xor(sm, msk, 64);
    const float inv = 1.0f / sm;
    const int r_att = wave * 16 + q4 * 4 + rr;
    #pragma unroll
    for (int tt = 0; tt < 8; tt++) {
      const int colj = (tt < 4) ? (tt * 16 + l15) : (64 + (tt - 4) * 16 + l15);
      WL[r_att * 136 + colj] = f2bf(ex[tt] * inv);
    }
  }

  __syncthreads();

  // merged = W[16x128] @ V'[128x64] per wave
  f32x4 accm[4];
  #pragma unroll
  for (int j = 0; j < 4; j++) accm[j] = (f32x4){0.f, 0.f, 0.f, 0.f};
  #pragma unroll
  for (int s = 0; s < 4; s++) {
    const bf16x8 aw = *(const bf16x8*)(WL + (wave * 16 + l15) * 136 + s * 32 + q4 * 8);
    #pragma unroll
    for (int j = 0; j < 4; j++) {
      const bf16x8 bv = *(const bf16x8*)(VT + (j * 16 + l15) * 136 + s * 32 + q4 * 8);
      accm[j] = __builtin_amdgcn_mfma_f32_16x16x32_bf16(aw, bv, accm[j], 0, 0, 0);
    }
  }

  #pragma unroll
  for (int j = 0; j < 4; j++) {
    #pragma unroll
    for (int rr = 0; rr < 4; rr++) {
      const int row = wave * 16 + q4 * 4 + rr;
      const int col = j * 16 + l15;
      att[((size_t)(b * LL + n * SEGC + row)) * 1024 + h * 64 + col] = f2bf(accm[j][rr]);
    }
  }
}

// ---------------------------------------------------------------------------
extern "C" void kernel_launch(void* const* d_in, const int* in_sizes, int n_in,
                              void* d_out, int out_size, void* d_ws, size_t ws_size,
                              hipStream_t stream) {
  const float* x  = (const float*)d_in[0];  // [B][L][DM] f32
  const float* wq = (const float*)d_in[1];  // [DM][H][HD]
  const float* wk = (const float*)d_in[2];
  const float* wv = (const float*)d_in[3];
  const float* wo = (const float*)d_in[4];  // [H][HD][DM]
  float* out = (float*)d_out;               // [B][L][DM] f32

  unsigned short* wsp   = (unsigned short*)d_ws;
  unsigned short* xb    = wsp;                       // 16,777,216 (aliased as attb later)
  unsigned short* qkv   = xb + 16777216;             // 50,331,648
  unsigned short* WqkvT = qkv + 50331648;            //  3,145,728
  unsigned short* woT   = WqkvT + 3145728;           //  1,048,576
  unsigned short* skb   = woT + 1048576;             //    262,144
  unsigned short* svb   = skb + 262144;              //    262,144
  unsigned short* attb  = xb;   // alias: xb dead after QKV GEMM
  // total: ~143.7 MB

  cvt_x<<<8192, 256, 0, stream>>>(x, xb);
  pack_w<<<16, 256, 0, stream>>>(wq, wk, wv, wo, WqkvT, woT);
  gemm_bt<false><<<dim3(128, 24), 256, 0, stream>>>(xb, WqkvT, (void*)qkv, 3072);
  span_kernel<<<dim3(256, 16), 64, 0, stream>>>(qkv, skb, svb);
  attn_kernel<<<dim3(256, 16), 256, 0, stream>>>(qkv, skb, svb, attb);
  gemm_bt<true><<<dim3(128, 8), 256, 0, stream>>>(attb, woT, (void*)out, 1024);
}

// Round 5
// 369.606 us; speedup vs baseline: 3.1591x; 1.5064x over previous
//
#include <hip/hip_runtime.h>

// Problem constants
#define BB    4
#define LL    4096
#define DM    1024
#define HH    16
#define SEGC  64
#define HDC   64
#define NSEGC 64
#define NEGV  -1.0e10f

typedef __bf16 bf16x8 __attribute__((ext_vector_type(8)));
typedef float  f32x4  __attribute__((ext_vector_type(4)));

__device__ __forceinline__ float bf2f(unsigned short s) {
  union { unsigned int u; float f; } x; x.u = ((unsigned int)s) << 16; return x.f;
}
__device__ __forceinline__ unsigned short f2bf(float f) {
  union { float f; unsigned int u; } x; x.f = f;
  unsigned int u = x.u;
  return (unsigned short)((u + 0x7fffu + ((u >> 16) & 1u)) >> 16);
}

// async global->LDS, 16 bytes per lane; LDS dest is wave-uniform base,
// lane i lands at l + i*16 bytes.
__device__ __forceinline__ void gl2lds16(const unsigned short* g, unsigned short* l) {
  __builtin_amdgcn_global_load_lds(
      (const __attribute__((address_space(1))) unsigned int*)g,
      (__attribute__((address_space(3))) unsigned int*)l,
      16, 0, 0);
}

// copy 16 bf16 from global (16B-aligned) to LDS (4B-aligned) via VGPR
__device__ __forceinline__ void g2lds16(unsigned short* dst, const unsigned short* src) {
  int4 a = *(const int4*)(src);
  int4 b = *(const int4*)(src + 8);
  unsigned int* d = (unsigned int*)dst;
  const unsigned int* pa = (const unsigned int*)&a;
  const unsigned int* pb = (const unsigned int*)&b;
  d[0]=pa[0]; d[1]=pa[1]; d[2]=pa[2]; d[3]=pa[3];
  d[4]=pb[0]; d[5]=pb[1]; d[6]=pb[2]; d[7]=pb[3];
}

// ---------------------------------------------------------------------------
// cvt_x: f32 -> bf16, 8 elems/thread
// ---------------------------------------------------------------------------
__global__ __launch_bounds__(256) void cvt_x(const float* __restrict__ x,
                                             unsigned short* __restrict__ xb) {
  const size_t i = ((size_t)blockIdx.x * 256 + threadIdx.x) * 8;
  float4 a = *(const float4*)(x + i);
  float4 b = *(const float4*)(x + i + 4);
  unsigned short o[8];
  o[0]=f2bf(a.x); o[1]=f2bf(a.y); o[2]=f2bf(a.z); o[3]=f2bf(a.w);
  o[4]=f2bf(b.x); o[5]=f2bf(b.y); o[6]=f2bf(b.z); o[7]=f2bf(b.w);
  *(int4*)(xb + i) = *(const int4*)o;
}

// ---------------------------------------------------------------------------
// transpose_w: LDS tile-transpose f32[1024][1024] -> bf16 [N][K].
// grid (16,16,4): z = source matrix (0=wq*0.125, 1=wk, 2=wv, 3=wo).
// Each block: 64x64 tile. Coalesced float4 reads, LDS [64][65] bf16,
// coalesced int4 writes.
// ---------------------------------------------------------------------------
__global__ __launch_bounds__(256) void transpose_w(
    const float* __restrict__ wq, const float* __restrict__ wk,
    const float* __restrict__ wv, const float* __restrict__ wo,
    unsigned short* __restrict__ WqkvT, unsigned short* __restrict__ woT) {
  __shared__ unsigned short TS[64 * 65];

  const int z  = blockIdx.z;
  const int bx = blockIdx.x;          // col-tile of source (= row-tile of dst)
  const int by = blockIdx.y;          // row-tile of source
  const int t  = threadIdx.x;

  const float* src; unsigned short* dst; float scale = 1.0f;
  if (z == 0)      { src = wq; dst = WqkvT;               scale = 0.125f; }
  else if (z == 1) { src = wk; dst = WqkvT + 1024 * 1024; }
  else if (z == 2) { src = wv; dst = WqkvT + 2048 * 1024; }
  else             { src = wo; dst = woT; }

  // read: 4 passes, each 256 threads x float4 = 16 rows x (16 x float4)
  const int rr = t >> 4;              // 0..15
  const int c4 = (t & 15) * 4;        // 0,4,..,60
  #pragma unroll
  for (int it = 0; it < 4; it++) {
    const int r = it * 16 + rr;       // 0..63 (source row within tile)
    float4 f = *(const float4*)(src + (size_t)(by * 64 + r) * 1024 + bx * 64 + c4);
    // TS[c][r] = src[r][c]
    TS[(c4 + 0) * 65 + r] = f2bf(f.x * scale);
    TS[(c4 + 1) * 65 + r] = f2bf(f.y * scale);
    TS[(c4 + 2) * 65 + r] = f2bf(f.z * scale);
    TS[(c4 + 3) * 65 + r] = f2bf(f.w * scale);
  }
  __syncthreads();

  // write: 2 passes, each 256 threads x int4(8 bf16) = 32 rows x (8 x int4)
  const int wr = t >> 3;              // 0..31
  const int w8 = (t & 7) * 8;         // 0,8,..,56
  #pragma unroll
  for (int it = 0; it < 2; it++) {
    const int n = it * 32 + wr;       // dst row within tile (= source col)
    unsigned short o[8];
    #pragma unroll
    for (int j = 0; j < 8; j++) o[j] = TS[n * 65 + w8 + j];
    *(int4*)(dst + (size_t)(bx * 64 + n) * 1024 + by * 64 + w8) = *(const int4*)o;
  }
}

// ---------------------------------------------------------------------------
// GEMM: C[M x N] = A[M x 1024] @ Bt[N x 1024]^T    (bf16 in, fp32 accum)
// m97 structure: 128x128 tile, BK=32, global_load_lds width=16 staging,
// 4 waves (2x2), each wave 4x4 of 16x16x32 bf16 MFMA.
// ---------------------------------------------------------------------------
template <bool C_F32>
__global__ __launch_bounds__(256) void gemm_bt(
    const unsigned short* __restrict__ A,
    const unsigned short* __restrict__ Bt,
    void* __restrict__ Cv,
    int ldc)
{
  __shared__ __align__(16) unsigned short As[128 * 32];  // [m][k]
  __shared__ __align__(16) unsigned short Bs[128 * 32];  // [n][k]

  const int t    = threadIdx.x;
  const int wave = t >> 6;
  const int lane = t & 63;
  const int l15  = lane & 15;
  const int q4   = lane >> 4;
  const int wm   = wave >> 1;
  const int wn   = wave & 1;
  const int m0   = blockIdx.x * 128;
  const int n0   = blockIdx.y * 128;

  // staging: one global_load_lds issue = 64 lanes x 16B = 16 rows of 64B
  const int srow = lane >> 2;
  const int scol = (lane & 3) * 8;

  f32x4 acc[4][4];
  #pragma unroll
  for (int i = 0; i < 4; i++)
    #pragma unroll
    for (int j = 0; j < 4; j++)
      acc[i][j] = (f32x4){0.f, 0.f, 0.f, 0.f};

  for (int k0 = 0; k0 < 1024; k0 += 32) {
    __syncthreads();
    #pragma unroll
    for (int i = 0; i < 2; i++) {
      const int c = wave * 2 + i;        // chunk 0..7 (16 rows each)
      gl2lds16(A  + (size_t)(m0 + c * 16 + srow) * 1024 + k0 + scol, As + c * 512);
      gl2lds16(Bt + (size_t)(n0 + c * 16 + srow) * 1024 + k0 + scol, Bs + c * 512);
    }
    __syncthreads();

    bf16x8 af[4], bfr[4];
    #pragma unroll
    for (int i = 0; i < 4; i++)
      af[i] = *(const bf16x8*)(As + (wm * 64 + i * 16 + l15) * 32 + q4 * 8);
    #pragma unroll
    for (int j = 0; j < 4; j++)
      bfr[j] = *(const bf16x8*)(Bs + (wn * 64 + j * 16 + l15) * 32 + q4 * 8);
    #pragma unroll
    for (int i = 0; i < 4; i++)
      #pragma unroll
      for (int j = 0; j < 4; j++)
        acc[i][j] = __builtin_amdgcn_mfma_f32_16x16x32_bf16(af[i], bfr[j], acc[i][j], 0, 0, 0);
  }

  #pragma unroll
  for (int i = 0; i < 4; i++) {
    #pragma unroll
    for (int j = 0; j < 4; j++) {
      const int col = n0 + wn * 64 + j * 16 + l15;
      #pragma unroll
      for (int r = 0; r < 4; r++) {
        const int row = m0 + wm * 64 + i * 16 + q4 * 4 + r;
        if (C_F32) ((float*)Cv)[(size_t)row * ldc + col] = acc[i][j][r];
        else ((unsigned short*)Cv)[(size_t)row * ldc + col] = f2bf(acc[i][j][r]);
      }
    }
  }
}

// ---------------------------------------------------------------------------
// Span kernel: per (chunk c, head h). qkv strided [row][3072]: q|k|v.
// ---------------------------------------------------------------------------
__global__ __launch_bounds__(64) void span_kernel(
    const unsigned short* __restrict__ qkv,
    unsigned short* __restrict__ spanK,   // [256][16][64]
    unsigned short* __restrict__ spanV)   // [256][16][64]
{
  __shared__ unsigned short QS[64 * 66], KS[64 * 66], VS[64 * 66];
  __shared__ float mqs[64], ws[64];

  const int c = blockIdx.x;        // 0..255
  const int h = blockIdx.y;        // 0..15
  const int b = c >> 6, n = c & 63;
  const int t = threadIdx.x;       // 0..63

  const size_t rowbase = ((size_t)(b * LL + n * SEGC + t)) * 3072 + h * 64;
  #pragma unroll
  for (int j = 0; j < 4; j++) {
    g2lds16(QS + t * 66 + j * 16, qkv + rowbase + j * 16);
    g2lds16(KS + t * 66 + j * 16, qkv + rowbase + 1024 + j * 16);
    g2lds16(VS + t * 66 + j * 16, qkv + rowbase + 2048 + j * 16);
  }
  __syncthreads();

  float mq = -3.0e38f, sk = -3.0e38f;
  for (int r = 0; r < 64; r++) {
    mq = fmaxf(mq, bf2f(QS[r * 66 + t]));
    sk = fmaxf(sk, bf2f(KS[r * 66 + t]));
  }
  mqs[t] = mq;
  spanK[((size_t)c * 16 + h) * 64 + t] = f2bf(sk);
  __syncthreads();

  float logit = 0.f;
  for (int d = 0; d < 64; d++) logit += mqs[d] * bf2f(KS[t * 66 + d]);
  float m = logit;
  #pragma unroll
  for (int off = 32; off; off >>= 1) m = fmaxf(m, __shfl_xor(m, off, 64));
  float e = __expf(logit - m);
  float s = e;
  #pragma unroll
  for (int off = 32; off; off >>= 1) s += __shfl_xor(s, off, 64);
  ws[t] = e / s;
  __syncthreads();

  float sv = 0.f;
  for (int kk = 0; kk < 64; kk++) sv += ws[kk] * bf2f(VS[kk * 66 + t]);
  spanV[((size_t)c * 16 + h) * 64 + t] = f2bf(sv);
}

// ---------------------------------------------------------------------------
// Joint attention kernel (MFMA): per (chunk c, head h), 4 waves.
// ---------------------------------------------------------------------------
__global__ __launch_bounds__(256) void attn_kernel(
    const unsigned short* __restrict__ qkv,
    const unsigned short* __restrict__ spanK,
    const unsigned short* __restrict__ spanV,
    unsigned short* __restrict__ att)
{
  __shared__ unsigned short VT[64 * 136];  // [f][k'], k' = joint key 0..127
  __shared__ unsigned short WL[64 * 136];  // [att row][k'] weights (bf16)

  const int c = blockIdx.x;          // 0..255
  const int h = blockIdx.y;          // 0..15
  const int b = c >> 6, n = c & 63;
  const int t = threadIdx.x;
  const int wave = t >> 6;
  const int lane = t & 63;
  const int l15  = lane & 15;
  const int q4   = lane >> 4;

  // stage V' = concat(V, spanV) transposed into VT[f][k']
  #pragma unroll
  for (int it = 0; it < 4; it++) {
    const int idx = t + 256 * it;       // 0..1023
    const int kp  = idx >> 3;           // joint key 0..127
    const int fc  = (idx & 7) * 8;
    const unsigned short* src;
    if (kp < 64)
      src = qkv + ((size_t)(b * LL + n * SEGC + kp)) * 3072 + 2048 + h * 64 + fc;
    else
      src = spanV + ((size_t)(b * 64 + (kp - 64)) * 16 + h) * 64 + fc;
    int4 val = *(const int4*)src;
    const unsigned short* e = (const unsigned short*)&val;
    #pragma unroll
    for (int i = 0; i < 8; i++) VT[(fc + i) * 136 + kp] = e[i];
  }

  // logits: Q @ K'^T via MFMA, fragments direct from global
  bf16x8 af[2];
  {
    const size_t qbase = ((size_t)(b * LL + n * SEGC + wave * 16 + l15)) * 3072
                         + h * 64 + q4 * 8;
    af[0] = *(const bf16x8*)(qkv + qbase);
    af[1] = *(const bf16x8*)(qkv + qbase + 32);
  }

  f32x4 accl[8];
  #pragma unroll
  for (int tt = 0; tt < 8; tt++) accl[tt] = (f32x4){0.f, 0.f, 0.f, 0.f};

  #pragma unroll
  for (int s = 0; s < 2; s++) {
    bf16x8 bfr[8];
    #pragma unroll
    for (int tt = 0; tt < 8; tt++) {
      const unsigned short* src;
      if (tt < 4)
        src = qkv + ((size_t)(b * LL + n * SEGC + tt * 16 + l15)) * 3072
              + 1024 + h * 64 + s * 32 + q4 * 8;
      else
        src = spanK + ((size_t)((b * 64 + (tt - 4) * 16 + l15) * 16 + h)) * 64
              + s * 32 + q4 * 8;
      bfr[tt] = *(const bf16x8*)src;
    }
    #pragma unroll
    for (int tt = 0; tt < 8; tt++)
      accl[tt] = __builtin_amdgcn_mfma_f32_16x16x32_bf16(af[s], bfr[tt], accl[tt], 0, 0, 0);
  }

  // mask
  #pragma unroll
  for (int tt = 0; tt < 8; tt++) {
    const int col = (tt & 3) * 16 + l15;
    #pragma unroll
    for (int rr = 0; rr < 4; rr++) {
      const int r_att = wave * 16 + q4 * 4 + rr;
      const bool valid = (tt < 4) ? (col <= r_att) : (col < n);
      if (!valid) accl[tt][rr] = NEGV;
    }
  }

  // wave-private row softmax; weights -> WL (bf16)
  #pragma unroll
  for (int rr = 0; rr < 4; rr++) {
    float mx = accl[0][rr];
    #pragma unroll
    for (int tt = 1; tt < 8; tt++) mx = fmaxf(mx, accl[tt][rr]);
    #pragma unroll
    for (int msk = 1; msk < 16; msk <<= 1) mx = fmaxf(mx, __shfl_xor(mx, msk, 64));
    float sm = 0.f;
    float ex[8];
    #pragma unroll
    for (int tt = 0; tt < 8; tt++) { ex[tt] = __expf(accl[tt][rr] - mx); sm += ex[tt]; }
    #pragma unroll
    for (int msk = 1; msk < 16; msk <<= 1) sm += __shfl_xor(sm, msk, 64);
    const float inv = 1.0f / sm;
    const int r_att = wave * 16 + q4 * 4 + rr;
    #pragma unroll
    for (int tt = 0; tt < 8; tt++) {
      const int colj = (tt < 4) ? (tt * 16 + l15) : (64 + (tt - 4) * 16 + l15);
      WL[r_att * 136 + colj] = f2bf(ex[tt] * inv);
    }
  }

  __syncthreads();

  // merged = W[16x128] @ V'[128x64] per wave
  f32x4 accm[4];
  #pragma unroll
  for (int j = 0; j < 4; j++) accm[j] = (f32x4){0.f, 0.f, 0.f, 0.f};
  #pragma unroll
  for (int s = 0; s < 4; s++) {
    const bf16x8 aw = *(const bf16x8*)(WL + (wave * 16 + l15) * 136 + s * 32 + q4 * 8);
    #pragma unroll
    for (int j = 0; j < 4; j++) {
      const bf16x8 bv = *(const bf16x8*)(VT + (j * 16 + l15) * 136 + s * 32 + q4 * 8);
      accm[j] = __builtin_amdgcn_mfma_f32_16x16x32_bf16(aw, bv, accm[j], 0, 0, 0);
    }
  }

  #pragma unroll
  for (int j = 0; j < 4; j++) {
    #pragma unroll
    for (int rr = 0; rr < 4; rr++) {
      const int row = wave * 16 + q4 * 4 + rr;
      const int col = j * 16 + l15;
      att[((size_t)(b * LL + n * SEGC + row)) * 1024 + h * 64 + col] = f2bf(accm[j][rr]);
    }
  }
}

// ---------------------------------------------------------------------------
extern "C" void kernel_launch(void* const* d_in, const int* in_sizes, int n_in,
                              void* d_out, int out_size, void* d_ws, size_t ws_size,
                              hipStream_t stream) {
  const float* x  = (const float*)d_in[0];  // [B][L][DM] f32
  const float* wq = (const float*)d_in[1];  // [DM][H][HD]
  const float* wk = (const float*)d_in[2];
  const float* wv = (const float*)d_in[3];
  const float* wo = (const float*)d_in[4];  // [H][HD][DM]
  float* out = (float*)d_out;               // [B][L][DM] f32

  unsigned short* wsp   = (unsigned short*)d_ws;
  unsigned short* xb    = wsp;                       // 16,777,216 (aliased as attb later)
  unsigned short* qkv   = xb + 16777216;             // 50,331,648
  unsigned short* WqkvT = qkv + 50331648;            //  3,145,728
  unsigned short* woT   = WqkvT + 3145728;           //  1,048,576
  unsigned short* skb   = woT + 1048576;             //    262,144
  unsigned short* svb   = skb + 262144;              //    262,144
  unsigned short* attb  = xb;   // alias: xb dead after QKV GEMM
  // total: ~143.7 MB

  cvt_x<<<8192, 256, 0, stream>>>(x, xb);
  transpose_w<<<dim3(16, 16, 4), 256, 0, stream>>>(wq, wk, wv, wo, WqkvT, woT);
  gemm_bt<false><<<dim3(128, 24), 256, 0, stream>>>(xb, WqkvT, (void*)qkv, 3072);
  span_kernel<<<dim3(256, 16), 64, 0, stream>>>(qkv, skb, svb);
  attn_kernel<<<dim3(256, 16), 256, 0, stream>>>(qkv, skb, svb, attb);
  gemm_bt<true><<<dim3(128, 8), 256, 0, stream>>>(attb, woT, (void*)out, 1024);
}